// Round 5
// baseline (377.761 us; speedup 1.0000x reference)
//
#include <hip/hip_runtime.h>
#include <math.h>
#include <float.h>

#define BN 32
#define CH 3
#define HH 512
#define WW 512
#define NP 4
#define EPS 128
#define HALF 64
#define MARGIN 32

#define NT 4096                                  // 64x64 grid of 8x8 tiles per map
#define PATCH_ELEMS (BN * NP * CH * EPS * EPS)   // 6291456
#define F4_PER_MAP (NP * CH * EPS * EPS / 4)     // 49152 (12 planes * 4096 f4)
#define NSLICE 8
#define F4_PER_SLICE (F4_PER_MAP / NSLICE)       // 6144
#define NBLK (BN * NSLICE)                       // 256 blocks: co-residency safe

// ws layout: tiles float2[BN*NT] (1MB) | done int[BN] | flags int[BN*NP]

// ---- tiny init: zero done counters + flags (ws is poisoned each iter) ------
__global__ void init_ws(int* __restrict__ done, int* __restrict__ flags)
{
    const int t = threadIdx.x;
    if (t < BN) done[t] = 0;
    if (t < BN * NP) flags[t] = 0;
}

// ---- fused: cooperative tile scan + 1x lazy selection + flagged extraction -
__global__ __launch_bounds__(1024)
void fused(const float* __restrict__ images,
           const float* __restrict__ umaps,
           float2* __restrict__ tiles,
           int* __restrict__ done,
           int* __restrict__ flags,
           float* __restrict__ out)
{
    const int tid   = threadIdx.x;
    const int lane  = tid & 63;
    const int wave  = tid >> 6;
    const int b     = blockIdx.x & (BN - 1);
    const int slice = blockIdx.x >> 5;            // 0..7; same-map blocks share XCD
    const int nwant = slice >> 1;                 // the one patch this block extracts
    const float* __restrict__ um = umaps + (size_t)b * HH * WW;
    float* coords_out = out + PATCH_ELEMS;

    __shared__ float2   tvi[NT];
    __shared__ float2   l2[64];
    __shared__ unsigned dirty[128];
    __shared__ int      boxes[NP][4];
    __shared__ int      spx1, spy1;               // accepted (x1,y1) for patch nwant

    // ======== Stage A: scan own 1/8 of the map (512 tiles, no redundancy) ====
    if (tid < 512) {
        const int t  = slice * 512 + tid;
        const int tx = t & 63, ty = t >> 6;
        const int x0 = tx << 3, y0 = ty << 3;
        float bv = -INFINITY; int bi = 0x7fffffff;
        #pragma unroll
        for (int r = 0; r < 8; ++r) {
            const int rowbase = (y0 + r) * WW + x0;
            const float4 a = *(const float4*)(um + rowbase);
            const float4 c = *(const float4*)(um + rowbase + 4);
            if (a.x > bv) { bv = a.x; bi = rowbase + 0; }
            if (a.y > bv) { bv = a.y; bi = rowbase + 1; }
            if (a.z > bv) { bv = a.z; bi = rowbase + 2; }
            if (a.w > bv) { bv = a.w; bi = rowbase + 3; }
            if (c.x > bv) { bv = c.x; bi = rowbase + 4; }
            if (c.y > bv) { bv = c.y; bi = rowbase + 5; }
            if (c.z > bv) { bv = c.z; bi = rowbase + 6; }
            if (c.w > bv) { bv = c.w; bi = rowbase + 7; }
        }
        tiles[b * NT + t] = make_float2(bv, __int_as_float(bi));
    }
    __threadfence();
    __syncthreads();
    if (tid == 0) atomicAdd(&done[b], 1);

    if (slice == 0) {
        // ======== Producer: selection, ONCE per map =========================
        if (tid == 0) {
            while (__hip_atomic_load(&done[b], __ATOMIC_ACQUIRE,
                                     __HIP_MEMORY_SCOPE_AGENT) < NSLICE)
                __builtin_amdgcn_s_sleep(1);
        }
        __syncthreads();
        __threadfence();

        // tile-cache readback: L1-bypassing agent loads (written by sibling blocks)
        {
            const unsigned long long* __restrict__ src =
                (const unsigned long long*)(tiles + (size_t)b * NT);
            unsigned long long* dst = (unsigned long long*)tvi;
            #pragma unroll
            for (int i = 0; i < 4; ++i)
                dst[tid + (i << 10)] = __hip_atomic_load(&src[tid + (i << 10)],
                        __ATOMIC_RELAXED, __HIP_MEMORY_SCOPE_AGENT);
        }
        if (tid < 128) dirty[tid] = 0u;
        if (tid < NP) { boxes[tid][0] = 0; boxes[tid][1] = 0; boxes[tid][2] = 0; boxes[tid][3] = 0; }
        __syncthreads();

        // level2 build: 16 waves x 4 rows
        for (int r = wave; r < 64; r += 16) {
            const float2 e = tvi[(r << 6) + lane];
            float v = e.x; int ix = __float_as_int(e.y);
            #pragma unroll
            for (int off = 32; off > 0; off >>= 1) {
                const float ov = __shfl_down(v, off);
                const int   oi = __shfl_down(ix, off);
                if (ov > v || (ov == v && oi < ix)) { v = ov; ix = oi; }
            }
            if (lane == 0) l2[r] = make_float2(v, __int_as_float(ix));
        }
        __syncthreads();

        for (int k = 0; k < NP; ++k) {
            if (wave == 0) {
                for (;;) {
                    const float2 e = l2[lane];
                    float v = e.x; int ix = __float_as_int(e.y);
                    #pragma unroll
                    for (int off = 32; off > 0; off >>= 1) {
                        const float ov = __shfl_down(v, off);
                        const int   oi = __shfl_down(ix, off);
                        if (ov > v || (ov == v && oi < ix)) { v = ov; ix = oi; }
                    }
                    ix = __shfl(ix, 0);
                    const int t = ((ix >> 12) << 6) | ((ix & 511) >> 3);
                    const bool isdirty = (dirty[t >> 5] >> (t & 31)) & 1u;
                    if (!isdirty) {
                        if (lane == 0) {
                            const int yc = ix >> 9, xc = ix & 511;
                            int x1 = max(0, xc - HALF), x2 = min(WW, xc + HALF);
                            int y1 = max(0, yc - HALF), y2 = min(HH, yc + HALF);
                            if (x2 - x1 < EPS) { if (x1 == 0) x2 = EPS; else x1 = x2 - EPS; }
                            if (y2 - y1 < EPS) { if (y1 == 0) y2 = EPS; else y1 = y2 - EPS; }
                            boxes[k][0] = max(x1 - MARGIN, 0);
                            boxes[k][1] = min(x2 + MARGIN, WW);
                            boxes[k][2] = max(y1 - MARGIN, 0);
                            boxes[k][3] = min(y2 + MARGIN, HH);
                            if (k == 0) { spx1 = x1; spy1 = y1; }
                            const int o = (b * NP + k) * 4;
                            coords_out[o + 0] = (float)x1;
                            coords_out[o + 1] = (float)y1;
                            coords_out[o + 2] = (float)x2;
                            coords_out[o + 3] = (float)y2;
                            // progressive publish: consumers of patch k go now
                            __hip_atomic_store(&flags[b * NP + k],
                                               0x40000000 | (y1 << 10) | x1,
                                               __ATOMIC_RELEASE, __HIP_MEMORY_SCOPE_AGENT);
                        }
                        break;
                    }
                    // recompute dirty tile t: 1 px per lane
                    const int ty = t >> 6, tx = t & 63;
                    const int y = (ty << 3) + (lane >> 3), x = (tx << 3) + (lane & 7);
                    float pv = um[y * WW + x];
                    int   pi = y * WW + x;
                    bool m = false;
                    #pragma unroll
                    for (int j = 0; j < NP; ++j)
                        m |= (y >= boxes[j][2] && y < boxes[j][3] &&
                              x >= boxes[j][0] && x < boxes[j][1]);
                    if (m) { pv = -INFINITY; pi = 0x7fffffff; }
                    float nv = pv; int ni = pi;
                    #pragma unroll
                    for (int off = 32; off > 0; off >>= 1) {
                        const float ov = __shfl_down(nv, off);
                        const int   oi = __shfl_down(ni, off);
                        if (ov > nv || (ov == nv && oi < ni)) { nv = ov; ni = oi; }
                    }
                    nv = __shfl(nv, 0); ni = __shfl(ni, 0);
                    if (lane == 0) {
                        tvi[t] = make_float2(nv, __int_as_float(ni));
                        dirty[t >> 5] &= ~(1u << (t & 31));
                    }
                    // repair level2 row ty (substitute new value in-register)
                    const float2 e2 = tvi[(ty << 6) + lane];
                    float rv2; int ri2;
                    if (lane == tx) { rv2 = nv; ri2 = ni; }
                    else            { rv2 = e2.x; ri2 = __float_as_int(e2.y); }
                    #pragma unroll
                    for (int off = 32; off > 0; off >>= 1) {
                        const float ov = __shfl_down(rv2, off);
                        const int   oi = __shfl_down(ri2, off);
                        if (ov > rv2 || (ov == rv2 && oi < ri2)) { rv2 = ov; ri2 = oi; }
                    }
                    if (lane == 0) l2[ty] = make_float2(rv2, __int_as_float(ri2));
                }
            }
            __syncthreads();

            if (k == NP - 1) break;

            // eager cheap invalidation for new box k
            const int ex1 = boxes[k][0], ex2 = boxes[k][1];
            const int ey1 = boxes[k][2], ey2 = boxes[k][3];
            const int tx1 = ex1 >> 3, tx2 = (ex2 - 1) >> 3;
            const int ty1 = ey1 >> 3, ty2 = (ey2 - 1) >> 3;
            const int wt  = tx2 - tx1 + 1;
            const int nt2 = wt * (ty2 - ty1 + 1);      // <= 625
            if (tid < nt2) {
                const int tx = tx1 + tid % wt;
                const int ty = ty1 + tid / wt;
                const int t  = (ty << 6) + tx;
                const int X1 = tx << 3, Y1 = ty << 3;
                if (X1 >= ex1 && X1 + 8 <= ex2 && Y1 >= ey1 && Y1 + 8 <= ey2)
                    tvi[t] = make_float2(-INFINITY, __int_as_float(0x7fffffff));
                else
                    atomicOr(&dirty[t >> 5], 1u << (t & 31));
            }
            __syncthreads();

            // repair level2 for affected rows
            for (int r = ty1 + wave; r <= ty2; r += 16) {
                const float2 e = tvi[(r << 6) + lane];
                float v = e.x; int ix = __float_as_int(e.y);
                #pragma unroll
                for (int off = 32; off > 0; off >>= 1) {
                    const float ov = __shfl_down(v, off);
                    const int   oi = __shfl_down(ix, off);
                    if (ov > v || (ov == v && oi < ix)) { v = ov; ix = oi; }
                }
                if (lane == 0) l2[r] = make_float2(v, __int_as_float(ix));
            }
            __syncthreads();
        }
    } else {
        // ======== Consumer: just wait for our patch's flag ===================
        if (tid == 0) {
            int f;
            while (((f = __hip_atomic_load(&flags[b * NP + nwant], __ATOMIC_ACQUIRE,
                                           __HIP_MEMORY_SCOPE_AGENT)) >> 30) == 0)
                __builtin_amdgcn_s_sleep(1);
            spx1 = f & 1023;
            spy1 = (f >> 10) & 1023;
        }
        __syncthreads();
    }

    // ======== Extraction: own map's 1/8 slice (single patch n = nwant) ======
    const int x1 = spx1, y1 = spy1;
    float4* __restrict__ out4 = (float4*)out;
    #pragma unroll
    for (int it = 0; it < 6; ++it) {
        const int il  = slice * F4_PER_SLICE + (it << 10) + tid;  // within-map f4 idx
        const int nc  = il >> 12;            // plane; n == nwant by construction
        const int c   = nc - nwant * 3;
        const int py  = (il >> 5) & 127;
        const int px0 = (il & 31) << 2;

        const float* __restrict__ src =
            images + (((size_t)b * CH + c) * HH + (y1 + py)) * WW + x1 + px0;
        out4[(size_t)b * F4_PER_MAP + il] = make_float4(src[0], src[1], src[2], src[3]);
    }
}

extern "C" void kernel_launch(void* const* d_in, const int* in_sizes, int n_in,
                              void* d_out, int out_size, void* d_ws, size_t ws_size,
                              hipStream_t stream) {
    const float* images = (const float*)d_in[0];
    const float* umaps  = (const float*)d_in[1];
    float* out          = (float*)d_out;
    float2* tiles       = (float2*)d_ws;                                // 1 MB
    int*    done        = (int*)((char*)d_ws + (size_t)BN * NT * sizeof(float2));
    int*    flags       = done + BN;

    init_ws<<<1, 256, 0, stream>>>(done, flags);
    fused<<<NBLK, 1024, 0, stream>>>(images, umaps, tiles, done, flags, out);
}

// Round 7
// 326.119 us; speedup vs baseline: 1.1584x; 1.1584x over previous
//
#include <hip/hip_runtime.h>
#include <hip/hip_cooperative_groups.h>
#include <math.h>
#include <float.h>

namespace cg = cooperative_groups;

#define BN 32
#define CH 3
#define HH 512
#define WW 512
#define NP 4
#define EPS 128
#define HALF 64
#define MARGIN 32

#define NT 4096                                  // 64x64 grid of 8x8 tiles per map
#define PATCH_ELEMS (BN * NP * CH * EPS * EPS)   // 6291456
#define F4_PER_MAP (NP * CH * EPS * EPS / 4)     // 49152 (12 planes * 4096 f4)
#define NSLICE 8
#define F4_PER_SLICE (F4_PER_MAP / NSLICE)       // 6144
#define NBLK (BN * NSLICE)                       // 256 blocks: 1/CU, coop-safe

typedef float nf4 __attribute__((ext_vector_type(4)));   // native vec for nt-store

// ws layout: tiles float2[BN*NT] (1MB) | l2g float2[BN*64] (16KB)
// Single cooperative kernel:
//   Phase A: each block scans its 1/8 of its map (no redundancy), writes
//            per-tile (max,idx) AND per-tile-row reduced (max,idx) to ws.
//   grid.sync()  (sanctioned device-wide barrier; R5's hand-rolled spin
//                 collapsed fabric BW to 240 GB/s -- never again)
//   Phase B: redundant deterministic selection per block, break at nwant;
//            patch-0 blocks skip the tile cache entirely (512B l2g read);
//            then stream own slice with non-temporal stores.
__global__ __launch_bounds__(1024)
void fused(const float* __restrict__ images,
           const float* __restrict__ umaps,
           float2* __restrict__ tiles,
           float2* __restrict__ l2g,
           float* __restrict__ out)
{
    const int tid   = threadIdx.x;
    const int lane  = tid & 63;
    const int wave  = tid >> 6;
    const int b     = blockIdx.x & (BN - 1);
    const int slice = blockIdx.x >> 5;            // 0..7
    const int nwant = slice >> 1;                 // the one patch this block extracts
    const float* __restrict__ um = umaps + (size_t)b * HH * WW;
    float* coords_out = out + PATCH_ELEMS;

    __shared__ float2   tvi[NT];
    __shared__ float2   l2[64];
    __shared__ unsigned dirty[128];
    __shared__ int      boxes[NP][4];
    __shared__ int      spx1, spy1;

    // ======== Phase A: scan own 1/8 of map (8 tile rows; wave == row) =======
    if (tid < 512) {
        const int t  = slice * 512 + tid;         // ty = slice*8 + wave, tx = lane
        const int tx = lane;
        const int ty = t >> 6;
        const int x0 = tx << 3, y0 = ty << 3;
        float bv = -INFINITY; int bi = 0x7fffffff;
        #pragma unroll
        for (int r = 0; r < 8; ++r) {
            const int rowbase = (y0 + r) * WW + x0;
            const float4 a = *(const float4*)(um + rowbase);
            const float4 c = *(const float4*)(um + rowbase + 4);
            if (a.x > bv) { bv = a.x; bi = rowbase + 0; }
            if (a.y > bv) { bv = a.y; bi = rowbase + 1; }
            if (a.z > bv) { bv = a.z; bi = rowbase + 2; }
            if (a.w > bv) { bv = a.w; bi = rowbase + 3; }
            if (c.x > bv) { bv = c.x; bi = rowbase + 4; }
            if (c.y > bv) { bv = c.y; bi = rowbase + 5; }
            if (c.z > bv) { bv = c.z; bi = rowbase + 6; }
            if (c.w > bv) { bv = c.w; bi = rowbase + 7; }
        }
        tiles[b * NT + t] = make_float2(bv, __int_as_float(bi));
        // free per-row reduction (wave holds the whole tile row)
        float rv = bv; int ri = bi;
        #pragma unroll
        for (int off = 32; off > 0; off >>= 1) {
            const float ov = __shfl_down(rv, off);
            const int   oi = __shfl_down(ri, off);
            if (ov > rv || (ov == rv && oi < ri)) { rv = ov; ri = oi; }
        }
        if (lane == 0) l2g[b * 64 + ty] = make_float2(rv, __int_as_float(ri));
    }
    __threadfence();
    cg::this_grid().sync();

    // ======== Phase B: selection ============================================
    if (nwant == 0) {
        // fast path: single-wave argmax straight from l2g (512B)
        if (wave == 0) {
            const float2 e = l2g[b * 64 + lane];
            float v = e.x; int ix = __float_as_int(e.y);
            #pragma unroll
            for (int off = 32; off > 0; off >>= 1) {
                const float ov = __shfl_down(v, off);
                const int   oi = __shfl_down(ix, off);
                if (ov > v || (ov == v && oi < ix)) { v = ov; ix = oi; }
            }
            ix = __shfl(ix, 0);
            if (lane == 0) {
                const int yc = ix >> 9, xc = ix & 511;
                int x1 = max(0, xc - HALF), x2 = min(WW, xc + HALF);
                int y1 = max(0, yc - HALF), y2 = min(HH, yc + HALF);
                if (x2 - x1 < EPS) { if (x1 == 0) x2 = EPS; else x1 = x2 - EPS; }
                if (y2 - y1 < EPS) { if (y1 == 0) y2 = EPS; else y1 = y2 - EPS; }
                spx1 = x1; spy1 = y1;
            }
        }
        __syncthreads();
    } else {
        // full path: tile cache + lazy-dirty greedy chain up to nwant
        {
            const float4* __restrict__ src = (const float4*)(tiles + (size_t)b * NT);
            float4* dst = (float4*)tvi;
            dst[tid]        = src[tid];
            dst[tid + 1024] = src[tid + 1024];
        }
        if (tid < 64)  l2[tid] = l2g[b * 64 + tid];       // precomputed level2
        if (tid < 128) dirty[tid] = 0u;
        if (tid < NP)  { boxes[tid][0] = 0; boxes[tid][1] = 0; boxes[tid][2] = 0; boxes[tid][3] = 0; }
        __syncthreads();

        for (int k = 0; k <= nwant; ++k) {
            if (wave == 0) {
                for (;;) {
                    const float2 e = l2[lane];
                    float v = e.x; int ix = __float_as_int(e.y);
                    #pragma unroll
                    for (int off = 32; off > 0; off >>= 1) {
                        const float ov = __shfl_down(v, off);
                        const int   oi = __shfl_down(ix, off);
                        if (ov > v || (ov == v && oi < ix)) { v = ov; ix = oi; }
                    }
                    ix = __shfl(ix, 0);
                    const int t = ((ix >> 12) << 6) | ((ix & 511) >> 3);
                    const bool isdirty = (dirty[t >> 5] >> (t & 31)) & 1u;
                    if (!isdirty) {
                        if (lane == 0) {
                            const int yc = ix >> 9, xc = ix & 511;
                            int x1 = max(0, xc - HALF), x2 = min(WW, xc + HALF);
                            int y1 = max(0, yc - HALF), y2 = min(HH, yc + HALF);
                            if (x2 - x1 < EPS) { if (x1 == 0) x2 = EPS; else x1 = x2 - EPS; }
                            if (y2 - y1 < EPS) { if (y1 == 0) y2 = EPS; else y1 = y2 - EPS; }
                            boxes[k][0] = max(x1 - MARGIN, 0);
                            boxes[k][1] = min(x2 + MARGIN, WW);
                            boxes[k][2] = max(y1 - MARGIN, 0);
                            boxes[k][3] = min(y2 + MARGIN, HH);
                            if (k == nwant) { spx1 = x1; spy1 = y1; }
                            if (slice == NSLICE - 1) {        // one coord writer per map
                                const int o = (b * NP + k) * 4;
                                coords_out[o + 0] = (float)x1;
                                coords_out[o + 1] = (float)y1;
                                coords_out[o + 2] = (float)x2;
                                coords_out[o + 3] = (float)y2;
                            }
                        }
                        break;
                    }
                    // recompute dirty tile t: 1 px per lane
                    const int ty = t >> 6, tx = t & 63;
                    const int y = (ty << 3) + (lane >> 3), x = (tx << 3) + (lane & 7);
                    float pv = um[y * WW + x];
                    int   pi = y * WW + x;
                    bool m = false;
                    #pragma unroll
                    for (int j = 0; j < NP; ++j)
                        m |= (y >= boxes[j][2] && y < boxes[j][3] &&
                              x >= boxes[j][0] && x < boxes[j][1]);
                    if (m) { pv = -INFINITY; pi = 0x7fffffff; }
                    float nv = pv; int ni = pi;
                    #pragma unroll
                    for (int off = 32; off > 0; off >>= 1) {
                        const float ov = __shfl_down(nv, off);
                        const int   oi = __shfl_down(ni, off);
                        if (ov > nv || (ov == nv && oi < ni)) { nv = ov; ni = oi; }
                    }
                    nv = __shfl(nv, 0); ni = __shfl(ni, 0);
                    if (lane == 0) {
                        tvi[t] = make_float2(nv, __int_as_float(ni));
                        dirty[t >> 5] &= ~(1u << (t & 31));
                    }
                    // repair level2 row ty (substitute new value in-register)
                    const float2 e2 = tvi[(ty << 6) + lane];
                    float rv2; int ri2;
                    if (lane == tx) { rv2 = nv; ri2 = ni; }
                    else            { rv2 = e2.x; ri2 = __float_as_int(e2.y); }
                    #pragma unroll
                    for (int off = 32; off > 0; off >>= 1) {
                        const float ov = __shfl_down(rv2, off);
                        const int   oi = __shfl_down(ri2, off);
                        if (ov > rv2 || (ov == rv2 && oi < ri2)) { rv2 = ov; ri2 = oi; }
                    }
                    if (lane == 0) l2[ty] = make_float2(rv2, __int_as_float(ri2));
                }
            }
            __syncthreads();

            if (k == nwant) break;

            // eager cheap invalidation for new box k
            const int ex1 = boxes[k][0], ex2 = boxes[k][1];
            const int ey1 = boxes[k][2], ey2 = boxes[k][3];
            const int tx1 = ex1 >> 3, tx2 = (ex2 - 1) >> 3;
            const int ty1 = ey1 >> 3, ty2 = (ey2 - 1) >> 3;
            const int wt  = tx2 - tx1 + 1;
            const int nt2 = wt * (ty2 - ty1 + 1);      // <= 625
            if (tid < nt2) {
                const int tx = tx1 + tid % wt;
                const int ty = ty1 + tid / wt;
                const int t  = (ty << 6) + tx;
                const int X1 = tx << 3, Y1 = ty << 3;
                if (X1 >= ex1 && X1 + 8 <= ex2 && Y1 >= ey1 && Y1 + 8 <= ey2)
                    tvi[t] = make_float2(-INFINITY, __int_as_float(0x7fffffff));
                else
                    atomicOr(&dirty[t >> 5], 1u << (t & 31));
            }
            __syncthreads();

            // repair level2 for affected rows
            for (int r = ty1 + wave; r <= ty2; r += 16) {
                const float2 e = tvi[(r << 6) + lane];
                float v = e.x; int ix = __float_as_int(e.y);
                #pragma unroll
                for (int off = 32; off > 0; off >>= 1) {
                    const float ov = __shfl_down(v, off);
                    const int   oi = __shfl_down(ix, off);
                    if (ov > v || (ov == v && oi < ix)) { v = ov; ix = oi; }
                }
                if (lane == 0) l2[r] = make_float2(v, __int_as_float(ix));
            }
            __syncthreads();
        }
    }

    // ======== Extraction: own map's 1/8 slice (single patch n = nwant) ======
    const int x1 = spx1, y1 = spy1;
    nf4* __restrict__ out4 = (nf4*)out;
    #pragma unroll
    for (int it = 0; it < 6; ++it) {
        const int il  = slice * F4_PER_SLICE + (it << 10) + tid;  // within-map f4 idx
        const int nc  = il >> 12;            // plane; n == nwant by construction
        const int c   = nc - nwant * 3;
        const int py  = (il >> 5) & 127;
        const int px0 = (il & 31) << 2;

        const float* __restrict__ src =
            images + (((size_t)b * CH + c) * HH + (y1 + py)) * WW + x1 + px0;
        const nf4 v = { src[0], src[1], src[2], src[3] };
        __builtin_nontemporal_store(v, &out4[(size_t)b * F4_PER_MAP + il]);
    }
}

extern "C" void kernel_launch(void* const* d_in, const int* in_sizes, int n_in,
                              void* d_out, int out_size, void* d_ws, size_t ws_size,
                              hipStream_t stream) {
    const float* images = (const float*)d_in[0];
    const float* umaps  = (const float*)d_in[1];
    float* out          = (float*)d_out;
    float2* tiles       = (float2*)d_ws;                                // 1 MB
    float2* l2g         = tiles + (size_t)BN * NT;                      // 16 KB

    void* args[] = { (void*)&images, (void*)&umaps, (void*)&tiles,
                     (void*)&l2g, (void*)&out };
    (void)hipLaunchCooperativeKernel((const void*)fused, dim3(NBLK), dim3(1024),
                                     args, 0, stream);
}

// Round 8
// 168.855 us; speedup vs baseline: 2.2372x; 1.9314x over previous
//
#include <hip/hip_runtime.h>
#include <math.h>
#include <float.h>

#define BN 32
#define CH 3
#define HH 512
#define WW 512
#define NP 4
#define EPS 128
#define HALF 64
#define MARGIN 32

#define NT 4096                                  // 64x64 grid of 8x8 tiles per map
#define PATCH_ELEMS (BN * NP * CH * EPS * EPS)   // 6291456
#define F4_PER_MAP (NP * CH * EPS * EPS / 4)     // 49152 (12 planes * 4096 f4)
#define NSLICE 16
#define F4_PER_SLICE (F4_PER_MAP / NSLICE)       // 3072
#define K1_NTHR 256
#define K1_NBLK (BN * NT / K1_NTHR)              // 512

typedef float nf4 __attribute__((ext_vector_type(4)));   // native vec for nt-store

// NOTE (R5/R7 lesson, twice-measured): in-kernel cross-block sync on MI355X
// (hand-rolled spin OR cg::grid.sync) costs >100us at this grid size. All
// cross-block dataflow goes through stream-ordered kernel boundaries.

// ============ K1: per-tile (max,argmax) for all maps, computed ONCE =========
// Each wave covers one full tile row (lane == tx) => free per-row reduction
// into l2g (the level-2 argmax table select blocks would otherwise rebuild).
__global__ __launch_bounds__(K1_NTHR)
void tile_scan(const float* __restrict__ umaps, float2* __restrict__ tiles,
               float2* __restrict__ l2g)
{
    const int g  = blockIdx.x * K1_NTHR + threadIdx.x;
    const int b  = g >> 12;                      // map
    const int t  = g & (NT - 1);                 // tile within map
    const int tx = t & 63, ty = t >> 6;          // wave-uniform ty, tx == lane
    const float* __restrict__ um = umaps + (size_t)b * HH * WW;
    const int x0 = tx << 3, y0 = ty << 3;
    float bv = -INFINITY; int bi = 0x7fffffff;
    #pragma unroll
    for (int r = 0; r < 8; ++r) {
        const int rowbase = (y0 + r) * WW + x0;
        const float4 a = *(const float4*)(um + rowbase);
        const float4 c = *(const float4*)(um + rowbase + 4);
        if (a.x > bv) { bv = a.x; bi = rowbase + 0; }
        if (a.y > bv) { bv = a.y; bi = rowbase + 1; }
        if (a.z > bv) { bv = a.z; bi = rowbase + 2; }
        if (a.w > bv) { bv = a.w; bi = rowbase + 3; }
        if (c.x > bv) { bv = c.x; bi = rowbase + 4; }
        if (c.y > bv) { bv = c.y; bi = rowbase + 5; }
        if (c.z > bv) { bv = c.z; bi = rowbase + 6; }
        if (c.w > bv) { bv = c.w; bi = rowbase + 7; }
    }
    tiles[g] = make_float2(bv, __int_as_float(bi));
    // free per-row reduction (wave holds the whole tile row)
    float rv = bv; int ri = bi;
    #pragma unroll
    for (int off = 32; off > 0; off >>= 1) {
        const float ov = __shfl_down(rv, off);
        const int   oi = __shfl_down(ri, off);
        if (ov > rv || (ov == rv && oi < ri)) { rv = ov; ri = oi; }
    }
    const int lane = threadIdx.x & 63;
    if (lane == 0) l2g[b * 64 + ty] = make_float2(rv, __int_as_float(ri));
}

// ============ K2: fused redundant lazy selection + slice extraction =========
// 512 blocks: b = blk&31 (XCD spread), slice = blk>>5, nwant = slice>>2.
// Patch-0 blocks: one 512B l2g read + single-wave argmax, then extract.
// Others: 32KB tile cache + l2 seeded from l2g + lazy-dirty chain to nwant.
// Deterministic => all blocks of a map agree. slice 15 writes coords.
__global__ __launch_bounds__(1024)
void select_extract(const float* __restrict__ images,
                    const float* __restrict__ umaps,
                    const float2* __restrict__ tiles,
                    const float2* __restrict__ l2g,
                    float* __restrict__ out)
{
    const int tid   = threadIdx.x;
    const int lane  = tid & 63;
    const int wave  = tid >> 6;
    const int b     = blockIdx.x & (BN - 1);
    const int slice = blockIdx.x >> 5;
    const int nwant = slice >> 2;                 // the one patch this block extracts
    const float* __restrict__ um = umaps + (size_t)b * HH * WW;
    float* coords_out = out + PATCH_ELEMS;

    __shared__ float2   tvi[NT];
    __shared__ float2   l2[64];
    __shared__ unsigned dirty[128];
    __shared__ int      boxes[NP][4];
    __shared__ int      spx1, spy1;

    if (nwant == 0) {
        // ---- fast path: single-wave argmax straight from l2g (512B) --------
        if (wave == 0) {
            const float2 e = l2g[b * 64 + lane];
            float v = e.x; int ix = __float_as_int(e.y);
            #pragma unroll
            for (int off = 32; off > 0; off >>= 1) {
                const float ov = __shfl_down(v, off);
                const int   oi = __shfl_down(ix, off);
                if (ov > v || (ov == v && oi < ix)) { v = ov; ix = oi; }
            }
            ix = __shfl(ix, 0);
            if (lane == 0) {
                const int yc = ix >> 9, xc = ix & 511;
                int x1 = max(0, xc - HALF), x2 = min(WW, xc + HALF);
                int y1 = max(0, yc - HALF), y2 = min(HH, yc + HALF);
                if (x2 - x1 < EPS) { if (x1 == 0) x2 = EPS; else x1 = x2 - EPS; }
                if (y2 - y1 < EPS) { if (y1 == 0) y2 = EPS; else y1 = y2 - EPS; }
                spx1 = x1; spy1 = y1;
            }
        }
        __syncthreads();
    } else {
        // ---- slow path: tile cache + lazy-dirty greedy chain to nwant ------
        {
            const float4* __restrict__ src = (const float4*)(tiles + (size_t)b * NT);
            float4* dst = (float4*)tvi;
            dst[tid]        = src[tid];
            dst[tid + 1024] = src[tid + 1024];
        }
        if (tid < 64)  l2[tid] = l2g[b * 64 + tid];       // precomputed level2
        if (tid < 128) dirty[tid] = 0u;
        if (tid < NP)  { boxes[tid][0] = 0; boxes[tid][1] = 0; boxes[tid][2] = 0; boxes[tid][3] = 0; }
        __syncthreads();

        for (int k = 0; k <= nwant; ++k) {
            if (wave == 0) {
                for (;;) {
                    const float2 e = l2[lane];
                    float v = e.x; int ix = __float_as_int(e.y);
                    #pragma unroll
                    for (int off = 32; off > 0; off >>= 1) {
                        const float ov = __shfl_down(v, off);
                        const int   oi = __shfl_down(ix, off);
                        if (ov > v || (ov == v && oi < ix)) { v = ov; ix = oi; }
                    }
                    ix = __shfl(ix, 0);
                    const int t = ((ix >> 12) << 6) | ((ix & 511) >> 3);
                    const bool isdirty = (dirty[t >> 5] >> (t & 31)) & 1u;
                    if (!isdirty) {
                        if (lane == 0) {
                            const int yc = ix >> 9, xc = ix & 511;
                            int x1 = max(0, xc - HALF), x2 = min(WW, xc + HALF);
                            int y1 = max(0, yc - HALF), y2 = min(HH, yc + HALF);
                            if (x2 - x1 < EPS) { if (x1 == 0) x2 = EPS; else x1 = x2 - EPS; }
                            if (y2 - y1 < EPS) { if (y1 == 0) y2 = EPS; else y1 = y2 - EPS; }
                            boxes[k][0] = max(x1 - MARGIN, 0);
                            boxes[k][1] = min(x2 + MARGIN, WW);
                            boxes[k][2] = max(y1 - MARGIN, 0);
                            boxes[k][3] = min(y2 + MARGIN, HH);
                            if (k == nwant) { spx1 = x1; spy1 = y1; }
                            if (slice == NSLICE - 1) {        // one coord writer per map
                                const int o = (b * NP + k) * 4;
                                coords_out[o + 0] = (float)x1;
                                coords_out[o + 1] = (float)y1;
                                coords_out[o + 2] = (float)x2;
                                coords_out[o + 3] = (float)y2;
                            }
                        }
                        break;
                    }
                    // recompute dirty tile t: 1 px per lane
                    const int ty = t >> 6, tx = t & 63;
                    const int y = (ty << 3) + (lane >> 3), x = (tx << 3) + (lane & 7);
                    float pv = um[y * WW + x];
                    int   pi = y * WW + x;
                    bool m = false;
                    #pragma unroll
                    for (int j = 0; j < NP; ++j)
                        m |= (y >= boxes[j][2] && y < boxes[j][3] &&
                              x >= boxes[j][0] && x < boxes[j][1]);
                    if (m) { pv = -INFINITY; pi = 0x7fffffff; }
                    float nv = pv; int ni = pi;
                    #pragma unroll
                    for (int off = 32; off > 0; off >>= 1) {
                        const float ov = __shfl_down(nv, off);
                        const int   oi = __shfl_down(ni, off);
                        if (ov > nv || (ov == nv && oi < ni)) { nv = ov; ni = oi; }
                    }
                    nv = __shfl(nv, 0); ni = __shfl(ni, 0);
                    if (lane == 0) {
                        tvi[t] = make_float2(nv, __int_as_float(ni));
                        dirty[t >> 5] &= ~(1u << (t & 31));
                    }
                    // repair level2 row ty (substitute new value in-register)
                    const float2 e2 = tvi[(ty << 6) + lane];
                    float rv2; int ri2;
                    if (lane == tx) { rv2 = nv; ri2 = ni; }
                    else            { rv2 = e2.x; ri2 = __float_as_int(e2.y); }
                    #pragma unroll
                    for (int off = 32; off > 0; off >>= 1) {
                        const float ov = __shfl_down(rv2, off);
                        const int   oi = __shfl_down(ri2, off);
                        if (ov > rv2 || (ov == rv2 && oi < ri2)) { rv2 = ov; ri2 = oi; }
                    }
                    if (lane == 0) l2[ty] = make_float2(rv2, __int_as_float(ri2));
                }
            }
            __syncthreads();

            if (k == nwant) break;

            // eager cheap invalidation for new box k
            const int ex1 = boxes[k][0], ex2 = boxes[k][1];
            const int ey1 = boxes[k][2], ey2 = boxes[k][3];
            const int tx1 = ex1 >> 3, tx2 = (ex2 - 1) >> 3;
            const int ty1 = ey1 >> 3, ty2 = (ey2 - 1) >> 3;
            const int wt  = tx2 - tx1 + 1;
            const int nt2 = wt * (ty2 - ty1 + 1);      // <= 625
            if (tid < nt2) {
                const int tx = tx1 + tid % wt;
                const int ty = ty1 + tid / wt;
                const int t  = (ty << 6) + tx;
                const int X1 = tx << 3, Y1 = ty << 3;
                if (X1 >= ex1 && X1 + 8 <= ex2 && Y1 >= ey1 && Y1 + 8 <= ey2)
                    tvi[t] = make_float2(-INFINITY, __int_as_float(0x7fffffff));
                else
                    atomicOr(&dirty[t >> 5], 1u << (t & 31));
            }
            __syncthreads();

            // repair level2 for affected rows
            for (int r = ty1 + wave; r <= ty2; r += 16) {
                const float2 e = tvi[(r << 6) + lane];
                float v = e.x; int ix = __float_as_int(e.y);
                #pragma unroll
                for (int off = 32; off > 0; off >>= 1) {
                    const float ov = __shfl_down(v, off);
                    const int   oi = __shfl_down(ix, off);
                    if (ov > v || (ov == v && oi < ix)) { v = ov; ix = oi; }
                }
                if (lane == 0) l2[r] = make_float2(v, __int_as_float(ix));
            }
            __syncthreads();
        }
    }

    // ---- extraction: own map's 1/16 slice (single patch n = nwant) ---------
    const int x1 = spx1, y1 = spy1;
    nf4* __restrict__ out4 = (nf4*)out;
    #pragma unroll
    for (int it = 0; it < 3; ++it) {
        const int il  = slice * F4_PER_SLICE + (it << 10) + tid;  // within-map f4 idx
        const int nc  = il >> 12;            // plane; n == nwant by construction
        const int c   = nc - nwant * 3;
        const int py  = (il >> 5) & 127;
        const int px0 = (il & 31) << 2;

        const float* __restrict__ src =
            images + (((size_t)b * CH + c) * HH + (y1 + py)) * WW + x1 + px0;
        const nf4 v = { src[0], src[1], src[2], src[3] };
        __builtin_nontemporal_store(v, &out4[(size_t)b * F4_PER_MAP + il]);
    }
}

extern "C" void kernel_launch(void* const* d_in, const int* in_sizes, int n_in,
                              void* d_out, int out_size, void* d_ws, size_t ws_size,
                              hipStream_t stream) {
    const float* images = (const float*)d_in[0];
    const float* umaps  = (const float*)d_in[1];
    float* out          = (float*)d_out;
    float2* tiles       = (float2*)d_ws;                                // 1 MB
    float2* l2g         = tiles + (size_t)BN * NT;                      // 16 KB

    tile_scan<<<K1_NBLK, K1_NTHR, 0, stream>>>(umaps, tiles, l2g);
    select_extract<<<BN * NSLICE, 1024, 0, stream>>>(images, umaps, tiles, l2g, out);
}